// Round 5
// baseline (4175.388 us; speedup 1.0000x reference)
//
#include <hip/hip_runtime.h>
#include <stdint.h>

// ---------------------------------------------------------------------------
// GRU encoder (B=128,T=512,D=512,H=512,L=256), MI355X gfx950.
//
// R5: tag-in-data h exchange. h element = dword (bf16<<16 | step_tag).
//   - producer: 4 fire-and-forget sc0 sc1 dword stores. NO drain, NO flag.
//   - consumer: speculative 32x dwordx4 load of all fragments (one vmcnt(0)),
//     MFMAs immediately; tag check (bad |= (d^t)&0xffff) overlaps on the
//     VALU pipe; __any(bad) -> retry whole block. Detect+load = ONE RT.
//   - safety: per-dword tags make partial arrival / stale data / mis-timed
//     waits all detectable; P stores h_{t+2} only after seeing all tags t+1,
//     which implies every wave's h_t reads completed -> no overwrite race.
//   - no memsets: t=0 skips h loads (h0=0); poison tag 0xAAAA != any t.
// IG re-laid out wave-tile-contiguous: recurrence reads 3 coalesced dwordx2
// per lane per step (was 12 scattered 2B loads).
// ---------------------------------------------------------------------------

typedef short short8 __attribute__((ext_vector_type(8)));
typedef float f32x4 __attribute__((ext_vector_type(4)));
typedef int int4v __attribute__((ext_vector_type(4)));
typedef unsigned int uint;

#define NB 128
#define NT 512
#define ND 512
#define NH 512
#define NG 1536  // 3H

__device__ __forceinline__ unsigned short f2bf(float f) {
  union { float f; unsigned u; } v; v.f = f;
  unsigned r = v.u + 0x7fffu + ((v.u >> 16) & 1u);  // RNE
  return (unsigned short)(r >> 16);
}
__device__ __forceinline__ float bf2f(unsigned short u) {
  union { unsigned u; float f; } v; v.u = ((unsigned)u) << 16; return v.f;
}
__device__ __forceinline__ float sigmoid_f(float x) {
  float e = __builtin_amdgcn_exp2f(-1.4426950408889634f * x);
  return __builtin_amdgcn_rcpf(1.0f + e);
}
__device__ __forceinline__ float tanh_f(float x) {
  float e = __builtin_amdgcn_exp2f(2.8853900817779268f * x);
  return 1.0f - 2.0f * __builtin_amdgcn_rcpf(1.0f + e);
}
__device__ __forceinline__ short8 pack8(float4 a, float4 b) {
  short8 s;
  s[0] = (short)f2bf(a.x); s[1] = (short)f2bf(a.y);
  s[2] = (short)f2bf(a.z); s[3] = (short)f2bf(a.w);
  s[4] = (short)f2bf(b.x); s[5] = (short)f2bf(b.y);
  s[6] = (short)f2bf(b.z); s[7] = (short)f2bf(b.w);
  return s;
}

// chunks 0..7: 16 coherent dwordx4 loads, offsets kk*128 + {0,16}. No wait.
__device__ __forceinline__ void load16_a(const uint* p, int4v a[16]) {
  asm volatile(
      "global_load_dwordx4 %0,  %16, off sc0 sc1\n\t"
      "global_load_dwordx4 %1,  %16, off offset:16 sc0 sc1\n\t"
      "global_load_dwordx4 %2,  %16, off offset:128 sc0 sc1\n\t"
      "global_load_dwordx4 %3,  %16, off offset:144 sc0 sc1\n\t"
      "global_load_dwordx4 %4,  %16, off offset:256 sc0 sc1\n\t"
      "global_load_dwordx4 %5,  %16, off offset:272 sc0 sc1\n\t"
      "global_load_dwordx4 %6,  %16, off offset:384 sc0 sc1\n\t"
      "global_load_dwordx4 %7,  %16, off offset:400 sc0 sc1\n\t"
      "global_load_dwordx4 %8,  %16, off offset:512 sc0 sc1\n\t"
      "global_load_dwordx4 %9,  %16, off offset:528 sc0 sc1\n\t"
      "global_load_dwordx4 %10, %16, off offset:640 sc0 sc1\n\t"
      "global_load_dwordx4 %11, %16, off offset:656 sc0 sc1\n\t"
      "global_load_dwordx4 %12, %16, off offset:768 sc0 sc1\n\t"
      "global_load_dwordx4 %13, %16, off offset:784 sc0 sc1\n\t"
      "global_load_dwordx4 %14, %16, off offset:896 sc0 sc1\n\t"
      "global_load_dwordx4 %15, %16, off offset:912 sc0 sc1"
      : "=&v"(a[0]), "=&v"(a[1]), "=&v"(a[2]), "=&v"(a[3]),
        "=&v"(a[4]), "=&v"(a[5]), "=&v"(a[6]), "=&v"(a[7]),
        "=&v"(a[8]), "=&v"(a[9]), "=&v"(a[10]), "=&v"(a[11]),
        "=&v"(a[12]), "=&v"(a[13]), "=&v"(a[14]), "=&v"(a[15])
      : "v"(p)
      : "memory");
}
// chunks 8..15, then drain everything (covers block A too).
__device__ __forceinline__ void load16_b(const uint* p, int4v a[16]) {
  asm volatile(
      "global_load_dwordx4 %0,  %16, off offset:1024 sc0 sc1\n\t"
      "global_load_dwordx4 %1,  %16, off offset:1040 sc0 sc1\n\t"
      "global_load_dwordx4 %2,  %16, off offset:1152 sc0 sc1\n\t"
      "global_load_dwordx4 %3,  %16, off offset:1168 sc0 sc1\n\t"
      "global_load_dwordx4 %4,  %16, off offset:1280 sc0 sc1\n\t"
      "global_load_dwordx4 %5,  %16, off offset:1296 sc0 sc1\n\t"
      "global_load_dwordx4 %6,  %16, off offset:1408 sc0 sc1\n\t"
      "global_load_dwordx4 %7,  %16, off offset:1424 sc0 sc1\n\t"
      "global_load_dwordx4 %8,  %16, off offset:1536 sc0 sc1\n\t"
      "global_load_dwordx4 %9,  %16, off offset:1552 sc0 sc1\n\t"
      "global_load_dwordx4 %10, %16, off offset:1664 sc0 sc1\n\t"
      "global_load_dwordx4 %11, %16, off offset:1680 sc0 sc1\n\t"
      "global_load_dwordx4 %12, %16, off offset:1792 sc0 sc1\n\t"
      "global_load_dwordx4 %13, %16, off offset:1808 sc0 sc1\n\t"
      "global_load_dwordx4 %14, %16, off offset:1920 sc0 sc1\n\t"
      "global_load_dwordx4 %15, %16, off offset:1936 sc0 sc1\n\t"
      "s_waitcnt vmcnt(0)"
      : "=&v"(a[0]), "=&v"(a[1]), "=&v"(a[2]), "=&v"(a[3]),
        "=&v"(a[4]), "=&v"(a[5]), "=&v"(a[6]), "=&v"(a[7]),
        "=&v"(a[8]), "=&v"(a[9]), "=&v"(a[10]), "=&v"(a[11]),
        "=&v"(a[12]), "=&v"(a[13]), "=&v"(a[14]), "=&v"(a[15])
      : "v"(p)
      : "memory");
}

// 8 dwords (h<<16|tag) -> short8 A-fragment; accumulate tag mismatches.
__device__ __forceinline__ short8 unpack_check(int4v lo, int4v hi, uint tt,
                                               uint& bad) {
  uint d0 = (uint)lo[0], d1 = (uint)lo[1], d2 = (uint)lo[2], d3 = (uint)lo[3];
  uint d4 = (uint)hi[0], d5 = (uint)hi[1], d6 = (uint)hi[2], d7 = (uint)hi[3];
  bad |= (d0 ^ tt) & 0xffffu; bad |= (d1 ^ tt) & 0xffffu;
  bad |= (d2 ^ tt) & 0xffffu; bad |= (d3 ^ tt) & 0xffffu;
  bad |= (d4 ^ tt) & 0xffffu; bad |= (d5 ^ tt) & 0xffffu;
  bad |= (d6 ^ tt) & 0xffffu; bad |= (d7 ^ tt) & 0xffffu;
  int4v r;
  r[0] = (int)__builtin_amdgcn_perm(d1, d0, 0x07060302u);
  r[1] = (int)__builtin_amdgcn_perm(d3, d2, 0x07060302u);
  r[2] = (int)__builtin_amdgcn_perm(d5, d4, 0x07060302u);
  r[3] = (int)__builtin_amdgcn_perm(d7, d6, 0x07060302u);
  return __builtin_bit_cast(short8, r);
}

// ---------------------------------------------------------------------------
// IG = x @ Wih^T + bias, bf16, written in wave-tile layout:
// IG[(((bt*NT+t)*32+cc)*3+gt)*256 + (qc*16+l15c)*4 + ic]
//   bt = b>>4 (batch tile), cc = hcol>>4, gt = gate, qc=(b&15)>>2, ic=b&3.
// ---------------------------------------------------------------------------
__global__ __launch_bounds__(256) void ig_gemm(
    const float* __restrict__ x, const float* __restrict__ Wih,
    const float* __restrict__ bias, unsigned short* __restrict__ IG) {
  __shared__ unsigned short As[128 * 40];
  __shared__ unsigned short Bs[128 * 40];
  const int tid = threadIdx.x;
  const int bm = blockIdx.x, bn = blockIdx.y;
  const int lane = tid & 63, w = tid >> 6;
  const int wm = w >> 1, wn = w & 1;
  const int l15 = lane & 15, q = lane >> 4;

  f32x4 acc[4][4] = {};

  for (int kt = 0; kt < 16; ++kt) {
    __syncthreads();
#pragma unroll
    for (int j = 0; j < 4; ++j) {
      int fi = tid + 256 * j;
      int row = fi >> 3, kq = fi & 7;
      float4 v = *(const float4*)(x + (size_t)(bm * 128 + row) * ND + kt * 32 + kq * 4);
      ushort4 s = {f2bf(v.x), f2bf(v.y), f2bf(v.z), f2bf(v.w)};
      *(ushort4*)&As[row * 40 + kq * 4] = s;
    }
#pragma unroll
    for (int j = 0; j < 4; ++j) {
      int fi = tid + 256 * j;
      int row = fi >> 3, kq = fi & 7;
      float4 v = *(const float4*)(Wih + (size_t)(bn * 128 + row) * ND + kt * 32 + kq * 4);
      ushort4 s = {f2bf(v.x), f2bf(v.y), f2bf(v.z), f2bf(v.w)};
      *(ushort4*)&Bs[row * 40 + kq * 4] = s;
    }
    __syncthreads();

    short8 af[4], bf[4];
#pragma unroll
    for (int tm = 0; tm < 4; ++tm)
      af[tm] = *(const short8*)&As[(wm * 64 + tm * 16 + l15) * 40 + q * 8];
#pragma unroll
    for (int tn = 0; tn < 4; ++tn)
      bf[tn] = *(const short8*)&Bs[(wn * 64 + tn * 16 + l15) * 40 + q * 8];
#pragma unroll
    for (int tm = 0; tm < 4; ++tm)
#pragma unroll
      for (int tn = 0; tn < 4; ++tn)
        acc[tm][tn] = __builtin_amdgcn_mfma_f32_16x16x32_bf16(af[tm], bf[tn], acc[tm][tn], 0, 0, 0);
  }

  // epilogue: permuted store. block-uniform: b = bm>>2 (128-row tile = one b)
  const int b = bm >> 2;
  const int bt_ = b >> 4, qc = (b >> 2) & 3, ic = b & 3;
  const int tb = (bm & 3) * 128 + wm * 64;
#pragma unroll
  for (int tm = 0; tm < 4; ++tm) {
#pragma unroll
    for (int tn = 0; tn < 4; ++tn) {
      int C = bn * 128 + wn * 64 + tn * 16 + l15;
      int gt_ = C >> 9, hcol = C & 511, cc_ = hcol >> 4;
      float bb = bias[C];
#pragma unroll
      for (int i = 0; i < 4; ++i) {
        int t = tb + tm * 16 + q * 4 + i;
        size_t idx = ((((size_t)bt_ * NT + t) * 32 + cc_) * 3 + gt_) * 256
                     + (size_t)(qc * 16 + l15) * 4 + ic;
        IG[idx] = f2bf(acc[tm][tn][i] + bb);
      }
    }
  }
}

// ---------------------------------------------------------------------------
// Persistent GRU recurrence. 64 blocks x 256 threads.
// block = (group g of 32 batch rows, chunk c of 32 h-cols).
// wave (wm,wn): rows [bt*16,+16) (bt=g*2+wm), cols [cc*16,+16) (cc=c*2+wn).
// h buffer: dword per element, (bf16<<16)|tag, double-buffered by t parity.
// ---------------------------------------------------------------------------
template <bool USE_IG>
__global__ __launch_bounds__(256, 1) void gru_rec(
    const float* __restrict__ x, const float* __restrict__ Wih,
    const float* __restrict__ Whh, const float* __restrict__ bias,
    const float* __restrict__ bn, const unsigned short* __restrict__ IG,
    uint* __restrict__ hbuf, float* __restrict__ hfin) {
  const int tid = threadIdx.x;
  const int lane = tid & 63;
  const int w = tid >> 6;
  const int wm = w >> 1, wn = w & 1;
  const int l15 = lane & 15, q = lane >> 4;
  const int g = blockIdx.x >> 4;   // 4 groups
  const int c = blockIdx.x & 15;   // 16 col-chunks of 32
  const int b0 = g * 32;
  const int bt = g * 2 + wm;
  const int cc = c * 2 + wn;
  const int col = cc * 16 + l15;           // this lane's h column
  const int mrow = b0 + wm * 16 + l15;     // A-fragment batch row
  const int erow = b0 + wm * 16 + q * 4;   // C-layout batch row base

  // Whh B-fragments -> registers: 3 gates x 16 k-chunks (192 VGPRs)
  short8 bfr[3][16];
#pragma unroll
  for (int gt = 0; gt < 3; ++gt) {
    const float* src = Whh + (size_t)(gt * NH + col) * NH + q * 8;
#pragma unroll
    for (int kk = 0; kk < 16; ++kk) {
      float4 v0 = *(const float4*)(src + kk * 32);
      float4 v1 = *(const float4*)(src + kk * 32 + 4);
      bfr[gt][kk] = pack8(v0, v1);
    }
  }

  float bi_r = 0.f, bi_z = 0.f, bi_n = 0.f;
  if (!USE_IG) {
    bi_r = bias[col];
    bi_z = bias[NH + col];
    bi_n = bias[2 * NH + col];
  }
  const float bnv = bn[col];

  float hreg[4] = {0.f, 0.f, 0.f, 0.f};

  uint* const hb0 = hbuf;
  uint* const hb1 = hbuf + NB * NH;

  for (int t = 0; t < NT; ++t) {
    const uint* h32cur = (t & 1) ? hb1 : hb0;
    uint* h32nxt = (t & 1) ? hb0 : hb1;

    // IG for this step: 3 coalesced dwordx2 (wave-tile layout)
    float igr[4], igz[4], ign[4];
    if (USE_IG) {
      const unsigned short* igp =
          IG + (((size_t)bt * NT + t) * 32 + cc) * 768 + (size_t)(q * 16 + l15) * 4;
      uint2 gr = *(const uint2*)igp;
      uint2 gz = *(const uint2*)(igp + 256);
      uint2 gn = *(const uint2*)(igp + 512);
      igr[0] = bf2f((unsigned short)(gr.x & 0xffff));
      igr[1] = bf2f((unsigned short)(gr.x >> 16));
      igr[2] = bf2f((unsigned short)(gr.y & 0xffff));
      igr[3] = bf2f((unsigned short)(gr.y >> 16));
      igz[0] = bf2f((unsigned short)(gz.x & 0xffff));
      igz[1] = bf2f((unsigned short)(gz.x >> 16));
      igz[2] = bf2f((unsigned short)(gz.y & 0xffff));
      igz[3] = bf2f((unsigned short)(gz.y >> 16));
      ign[0] = bf2f((unsigned short)(gn.x & 0xffff));
      ign[1] = bf2f((unsigned short)(gn.x >> 16));
      ign[2] = bf2f((unsigned short)(gn.y & 0xffff));
      ign[3] = bf2f((unsigned short)(gn.y >> 16));
    }

    // fallback: x@Wih^T part, independent of h (outside retry loop)
    f32x4 axr = {0.f, 0.f, 0.f, 0.f};
    f32x4 axz = {0.f, 0.f, 0.f, 0.f};
    f32x4 axn = {0.f, 0.f, 0.f, 0.f};
    if (!USE_IG) {
#pragma unroll
      for (int kk = 0; kk < 16; ++kk) {
        const float* xp = x + ((size_t)mrow * NT + t) * ND + kk * 32 + q * 8;
        short8 xa = pack8(*(const float4*)xp, *(const float4*)(xp + 4));
#pragma unroll
        for (int gt = 0; gt < 3; ++gt) {
          const float* wp = Wih + (size_t)(gt * NH + col) * ND + kk * 32 + q * 8;
          short8 wf = pack8(*(const float4*)wp, *(const float4*)(wp + 4));
          if (gt == 0) axr = __builtin_amdgcn_mfma_f32_16x16x32_bf16(xa, wf, axr, 0, 0, 0);
          if (gt == 1) axz = __builtin_amdgcn_mfma_f32_16x16x32_bf16(xa, wf, axz, 0, 0, 0);
          if (gt == 2) axn = __builtin_amdgcn_mfma_f32_16x16x32_bf16(xa, wf, axn, 0, 0, 0);
        }
      }
    }

    // h part: speculative load + MFMA, validated by per-dword tags
    f32x4 ar = {0.f, 0.f, 0.f, 0.f};
    f32x4 az = {0.f, 0.f, 0.f, 0.f};
    f32x4 an = {0.f, 0.f, 0.f, 0.f};
    if (t > 0) {
      const uint* hp = h32cur + (size_t)mrow * NH + q * 8;
      int4v ra[16], rb[16];
      uint bad;
      do {
        load16_a(hp, ra);
        load16_b(hp, rb);  // ends s_waitcnt vmcnt(0): all 32 loads complete
        bad = 0;
        ar[0] = ar[1] = ar[2] = ar[3] = 0.f;
        az[0] = az[1] = az[2] = az[3] = 0.f;
        an[0] = an[1] = an[2] = an[3] = 0.f;
#pragma unroll
        for (int kk = 0; kk < 8; ++kk) {
          short8 afk = unpack_check(ra[2 * kk], ra[2 * kk + 1], (uint)t, bad);
          ar = __builtin_amdgcn_mfma_f32_16x16x32_bf16(afk, bfr[0][kk], ar, 0, 0, 0);
          az = __builtin_amdgcn_mfma_f32_16x16x32_bf16(afk, bfr[1][kk], az, 0, 0, 0);
          an = __builtin_amdgcn_mfma_f32_16x16x32_bf16(afk, bfr[2][kk], an, 0, 0, 0);
        }
#pragma unroll
        for (int kk = 0; kk < 8; ++kk) {
          short8 afk = unpack_check(rb[2 * kk], rb[2 * kk + 1], (uint)t, bad);
          ar = __builtin_amdgcn_mfma_f32_16x16x32_bf16(afk, bfr[0][8 + kk], ar, 0, 0, 0);
          az = __builtin_amdgcn_mfma_f32_16x16x32_bf16(afk, bfr[1][8 + kk], az, 0, 0, 0);
          an = __builtin_amdgcn_mfma_f32_16x16x32_bf16(afk, bfr[2][8 + kk], an, 0, 0, 0);
        }
      } while (__any(bad != 0));
    }

    // gates + h update
    uint sv[4];
#pragma unroll
    for (int i = 0; i < 4; ++i) {
      float xr = ar[i] + (USE_IG ? igr[i] : (axr[i] + bi_r));
      float xz = az[i] + (USE_IG ? igz[i] : (axz[i] + bi_z));
      float xin = USE_IG ? ign[i] : (axn[i] + bi_n);
      float r = sigmoid_f(xr);
      float z = sigmoid_f(xz);
      float n = tanh_f(xin + r * (an[i] + bnv));
      float h2 = (1.f - z) * n + z * hreg[i];
      hreg[i] = h2;
      sv[i] = ((uint)f2bf(h2) << 16) | (uint)(t + 1);
      if (t == NT - 1) hfin[(size_t)(erow + i) * NH + col] = h2;
    }
    if (t != NT - 1) {
      uint* p0 = h32nxt + (size_t)erow * NH + col;
      uint* p1 = p0 + 2 * NH;  // rows erow+2.. (offset 4096B exceeds imm range)
      asm volatile(
          "global_store_dword %0, %2, off sc0 sc1\n\t"
          "global_store_dword %0, %3, off offset:2048 sc0 sc1\n\t"
          "global_store_dword %1, %4, off sc0 sc1\n\t"
          "global_store_dword %1, %5, off offset:2048 sc0 sc1"
          :
          : "v"(p0), "v"(p1), "v"(sv[0]), "v"(sv[1]), "v"(sv[2]), "v"(sv[3])
          : "memory");
    }
  }
}

// ---------------------------------------------------------------------------
// out = h_T @ Wlin^T + blin; mu = cols [0,256), logvar = cols [256,512).
// ---------------------------------------------------------------------------
__global__ __launch_bounds__(256) void final_linear(
    const float* __restrict__ hfin, const float* __restrict__ Wlin,
    const float* __restrict__ blin, float* __restrict__ out) {
  __shared__ float sh[16 * 516];
  const int tid = threadIdx.x;
  const int b0 = blockIdx.y * 16, o0 = blockIdx.x * 16;

  for (int j = tid; j < 16 * 128; j += 256) {
    int row = j >> 7, kq = j & 127;
    *(float4*)&sh[row * 516 + kq * 4] =
        *(const float4*)(hfin + (size_t)(b0 + row) * NH + kq * 4);
  }
  __syncthreads();

  const int bi = tid & 15, oi = tid >> 4;
  const int o = o0 + oi;
  const float4* wp = (const float4*)(Wlin + (size_t)o * NH);
  float4 a4 = {0.f, 0.f, 0.f, 0.f};
  for (int k4 = 0; k4 < 128; ++k4) {
    float4 wv = wp[k4];
    float4 hv = *(const float4*)&sh[bi * 516 + k4 * 4];
    a4.x += wv.x * hv.x; a4.y += wv.y * hv.y;
    a4.z += wv.z * hv.z; a4.w += wv.w * hv.w;
  }
  float v = a4.x + a4.y + a4.z + a4.w + blin[o];
  int b = b0 + bi;
  if (o < 256) out[b * 256 + o] = v;
  else out[32768 + b * 256 + (o - 256)] = v;
}

// ---------------------------------------------------------------------------
extern "C" void kernel_launch(void* const* d_in, const int* in_sizes, int n_in,
                              void* d_out, int out_size, void* d_ws, size_t ws_size,
                              hipStream_t stream) {
  const float* x    = (const float*)d_in[0];
  const float* Wih  = (const float*)d_in[1];
  const float* Whh  = (const float*)d_in[2];
  const float* bias = (const float*)d_in[3];
  const float* bn   = (const float*)d_in[4];
  const float* Wlin = (const float*)d_in[5];
  const float* blin = (const float*)d_in[6];
  float* out = (float*)d_out;

  char* ws = (char*)d_ws;
  // layout: [h32 dword dbuf 524288][hfin 262144][IG 201326592]
  uint* hbuf          = (uint*)ws;
  float* hfin         = (float*)(ws + 524288);
  unsigned short* IG  = (unsigned short*)(ws + 786432);
  const size_t need_min = 786432;
  const size_t need_ig  = 786432 + (size_t)NB * NT * NG * 2;  // ~203 MB
  if (ws_size < need_min) return;
  // no memsets needed: t=0 skips h reads; tag scheme rejects 0xAA poison.

  const bool useIG = (ws_size >= need_ig);
  if (useIG) {
    ig_gemm<<<dim3(512, 12), 256, 0, stream>>>(x, Wih, bias, IG);
    gru_rec<true><<<64, 256, 0, stream>>>(x, Wih, Whh, bias, bn, IG, hbuf, hfin);
  } else {
    gru_rec<false><<<64, 256, 0, stream>>>(x, Wih, Whh, bias, bn, nullptr, hbuf, hfin);
  }
  final_linear<<<dim3(32, 8), 256, 0, stream>>>(hfin, Wlin, blin, out);
}

// Round 6
// 4029.331 us; speedup vs baseline: 1.0362x; 1.0362x over previous
//
#include <hip/hip_runtime.h>
#include <stdint.h>

// ---------------------------------------------------------------------------
// GRU encoder (B=128,T=512,D=512,H=512,L=256), MI355X gfx950.
//
// R6: tag-in-data, fixed. R5 failed because loads were issued before
// producers stored (every first try failed) and the retry body re-ran MFMAs.
// Changes:
//  - geometry: 8 groups x 16 rows, 8 blocks/group x 64 cols, 256 thr.
//    Wave owns 16 cols x 3 gates (192 VGPR Whh frags). 64 blocks, 1/CU.
//  - validate-then-compute: retry body = 32 dwordx4 loads + cheap tag check
//    (acc |= d^t, single mask at end); unpack+48 MFMA run once, after pass.
//  - IG[t+1] prefetched at top of step t (R5's verified wave-tile layout).
//  - no barriers / flags / drains / memsets. Poison 0xAAAA != any tag 1..511.
// h dword = (bf16 << 16) | step_tag, double-buffered by t parity.
// ---------------------------------------------------------------------------

typedef short short8 __attribute__((ext_vector_type(8)));
typedef float f32x4 __attribute__((ext_vector_type(4)));
typedef int int4v __attribute__((ext_vector_type(4)));
typedef unsigned int uint;

#define NB 128
#define NT 512
#define ND 512
#define NH 512
#define NG 1536  // 3H

__device__ __forceinline__ unsigned short f2bf(float f) {
  union { float f; unsigned u; } v; v.f = f;
  unsigned r = v.u + 0x7fffu + ((v.u >> 16) & 1u);  // RNE
  return (unsigned short)(r >> 16);
}
__device__ __forceinline__ float bf2f(unsigned short u) {
  union { unsigned u; float f; } v; v.u = ((unsigned)u) << 16; return v.f;
}
__device__ __forceinline__ float sigmoid_f(float x) {
  float e = __builtin_amdgcn_exp2f(-1.4426950408889634f * x);
  return __builtin_amdgcn_rcpf(1.0f + e);
}
__device__ __forceinline__ float tanh_f(float x) {
  float e = __builtin_amdgcn_exp2f(2.8853900817779268f * x);
  return 1.0f - 2.0f * __builtin_amdgcn_rcpf(1.0f + e);
}
__device__ __forceinline__ short8 pack8(float4 a, float4 b) {
  short8 s;
  s[0] = (short)f2bf(a.x); s[1] = (short)f2bf(a.y);
  s[2] = (short)f2bf(a.z); s[3] = (short)f2bf(a.w);
  s[4] = (short)f2bf(b.x); s[5] = (short)f2bf(b.y);
  s[6] = (short)f2bf(b.z); s[7] = (short)f2bf(b.w);
  return s;
}

// k-chunks 0..7: 16 coherent dwordx4 loads, offsets kk*128 + {0,16}. No wait.
__device__ __forceinline__ void load16_a(const uint* p, int4v a[16]) {
  asm volatile(
      "global_load_dwordx4 %0,  %16, off sc0 sc1\n\t"
      "global_load_dwordx4 %1,  %16, off offset:16 sc0 sc1\n\t"
      "global_load_dwordx4 %2,  %16, off offset:128 sc0 sc1\n\t"
      "global_load_dwordx4 %3,  %16, off offset:144 sc0 sc1\n\t"
      "global_load_dwordx4 %4,  %16, off offset:256 sc0 sc1\n\t"
      "global_load_dwordx4 %5,  %16, off offset:272 sc0 sc1\n\t"
      "global_load_dwordx4 %6,  %16, off offset:384 sc0 sc1\n\t"
      "global_load_dwordx4 %7,  %16, off offset:400 sc0 sc1\n\t"
      "global_load_dwordx4 %8,  %16, off offset:512 sc0 sc1\n\t"
      "global_load_dwordx4 %9,  %16, off offset:528 sc0 sc1\n\t"
      "global_load_dwordx4 %10, %16, off offset:640 sc0 sc1\n\t"
      "global_load_dwordx4 %11, %16, off offset:656 sc0 sc1\n\t"
      "global_load_dwordx4 %12, %16, off offset:768 sc0 sc1\n\t"
      "global_load_dwordx4 %13, %16, off offset:784 sc0 sc1\n\t"
      "global_load_dwordx4 %14, %16, off offset:896 sc0 sc1\n\t"
      "global_load_dwordx4 %15, %16, off offset:912 sc0 sc1"
      : "=&v"(a[0]), "=&v"(a[1]), "=&v"(a[2]), "=&v"(a[3]),
        "=&v"(a[4]), "=&v"(a[5]), "=&v"(a[6]), "=&v"(a[7]),
        "=&v"(a[8]), "=&v"(a[9]), "=&v"(a[10]), "=&v"(a[11]),
        "=&v"(a[12]), "=&v"(a[13]), "=&v"(a[14]), "=&v"(a[15])
      : "v"(p)
      : "memory");
}
// k-chunks 8..15, then drain everything (covers block A + IG prefetch too).
__device__ __forceinline__ void load16_b(const uint* p, int4v a[16]) {
  asm volatile(
      "global_load_dwordx4 %0,  %16, off offset:1024 sc0 sc1\n\t"
      "global_load_dwordx4 %1,  %16, off offset:1040 sc0 sc1\n\t"
      "global_load_dwordx4 %2,  %16, off offset:1152 sc0 sc1\n\t"
      "global_load_dwordx4 %3,  %16, off offset:1168 sc0 sc1\n\t"
      "global_load_dwordx4 %4,  %16, off offset:1280 sc0 sc1\n\t"
      "global_load_dwordx4 %5,  %16, off offset:1296 sc0 sc1\n\t"
      "global_load_dwordx4 %6,  %16, off offset:1408 sc0 sc1\n\t"
      "global_load_dwordx4 %7,  %16, off offset:1424 sc0 sc1\n\t"
      "global_load_dwordx4 %8,  %16, off offset:1536 sc0 sc1\n\t"
      "global_load_dwordx4 %9,  %16, off offset:1552 sc0 sc1\n\t"
      "global_load_dwordx4 %10, %16, off offset:1664 sc0 sc1\n\t"
      "global_load_dwordx4 %11, %16, off offset:1680 sc0 sc1\n\t"
      "global_load_dwordx4 %12, %16, off offset:1792 sc0 sc1\n\t"
      "global_load_dwordx4 %13, %16, off offset:1808 sc0 sc1\n\t"
      "global_load_dwordx4 %14, %16, off offset:1920 sc0 sc1\n\t"
      "global_load_dwordx4 %15, %16, off offset:1936 sc0 sc1\n\t"
      "s_waitcnt vmcnt(0)"
      : "=&v"(a[0]), "=&v"(a[1]), "=&v"(a[2]), "=&v"(a[3]),
        "=&v"(a[4]), "=&v"(a[5]), "=&v"(a[6]), "=&v"(a[7]),
        "=&v"(a[8]), "=&v"(a[9]), "=&v"(a[10]), "=&v"(a[11]),
        "=&v"(a[12]), "=&v"(a[13]), "=&v"(a[14]), "=&v"(a[15])
      : "v"(p)
      : "memory");
}

// 8 tagged dwords -> short8 A-fragment (data = high 16 bits).
__device__ __forceinline__ short8 unpack8(int4v lo, int4v hi) {
  int4v r;
  r[0] = (int)__builtin_amdgcn_perm((uint)lo[1], (uint)lo[0], 0x07060302u);
  r[1] = (int)__builtin_amdgcn_perm((uint)lo[3], (uint)lo[2], 0x07060302u);
  r[2] = (int)__builtin_amdgcn_perm((uint)hi[1], (uint)hi[0], 0x07060302u);
  r[3] = (int)__builtin_amdgcn_perm((uint)hi[3], (uint)hi[2], 0x07060302u);
  return __builtin_bit_cast(short8, r);
}

// ---------------------------------------------------------------------------
// IG = x @ Wih^T + bias, bf16, wave-tile layout (verified R5):
// IG[(((bt*NT+t)*32+cc)*3+gt)*256 + (q*16+l15)*4 + i], bt=b>>4, cc=hcol>>4.
// ---------------------------------------------------------------------------
__global__ __launch_bounds__(256) void ig_gemm(
    const float* __restrict__ x, const float* __restrict__ Wih,
    const float* __restrict__ bias, unsigned short* __restrict__ IG) {
  __shared__ unsigned short As[128 * 40];
  __shared__ unsigned short Bs[128 * 40];
  const int tid = threadIdx.x;
  const int bm = blockIdx.x, bn = blockIdx.y;
  const int lane = tid & 63, w = tid >> 6;
  const int wm = w >> 1, wn = w & 1;
  const int l15 = lane & 15, q = lane >> 4;

  f32x4 acc[4][4] = {};

  for (int kt = 0; kt < 16; ++kt) {
    __syncthreads();
#pragma unroll
    for (int j = 0; j < 4; ++j) {
      int fi = tid + 256 * j;
      int row = fi >> 3, kq = fi & 7;
      float4 v = *(const float4*)(x + (size_t)(bm * 128 + row) * ND + kt * 32 + kq * 4);
      ushort4 s = {f2bf(v.x), f2bf(v.y), f2bf(v.z), f2bf(v.w)};
      *(ushort4*)&As[row * 40 + kq * 4] = s;
    }
#pragma unroll
    for (int j = 0; j < 4; ++j) {
      int fi = tid + 256 * j;
      int row = fi >> 3, kq = fi & 7;
      float4 v = *(const float4*)(Wih + (size_t)(bn * 128 + row) * ND + kt * 32 + kq * 4);
      ushort4 s = {f2bf(v.x), f2bf(v.y), f2bf(v.z), f2bf(v.w)};
      *(ushort4*)&Bs[row * 40 + kq * 4] = s;
    }
    __syncthreads();

    short8 af[4], bf[4];
#pragma unroll
    for (int tm = 0; tm < 4; ++tm)
      af[tm] = *(const short8*)&As[(wm * 64 + tm * 16 + l15) * 40 + q * 8];
#pragma unroll
    for (int tn = 0; tn < 4; ++tn)
      bf[tn] = *(const short8*)&Bs[(wn * 64 + tn * 16 + l15) * 40 + q * 8];
#pragma unroll
    for (int tm = 0; tm < 4; ++tm)
#pragma unroll
      for (int tn = 0; tn < 4; ++tn)
        acc[tm][tn] = __builtin_amdgcn_mfma_f32_16x16x32_bf16(af[tm], bf[tn], acc[tm][tn], 0, 0, 0);
  }

  const int b = bm >> 2;
  const int bt_ = b >> 4, qc = (b >> 2) & 3, ic = b & 3;
  const int tb = (bm & 3) * 128 + wm * 64;
#pragma unroll
  for (int tm = 0; tm < 4; ++tm) {
#pragma unroll
    for (int tn = 0; tn < 4; ++tn) {
      int C = bn * 128 + wn * 64 + tn * 16 + l15;
      int gt_ = C >> 9, hcol = C & 511, cc_ = hcol >> 4;
      float bb = bias[C];
#pragma unroll
      for (int i = 0; i < 4; ++i) {
        int t = tb + tm * 16 + q * 4 + i;
        size_t idx = ((((size_t)bt_ * NT + t) * 32 + cc_) * 3 + gt_) * 256
                     + (size_t)(qc * 16 + l15) * 4 + ic;
        IG[idx] = f2bf(acc[tm][tn][i] + bb);
      }
    }
  }
}

// ---------------------------------------------------------------------------
// Persistent GRU recurrence. 64 blocks x 256 threads.
// block = (group g: 16 batch rows, chunk cb: 64 h-cols). wave w: 16 cols.
// ---------------------------------------------------------------------------
template <bool USE_IG>
__global__ __launch_bounds__(256, 1) void gru_rec(
    const float* __restrict__ x, const float* __restrict__ Wih,
    const float* __restrict__ Whh, const float* __restrict__ bias,
    const float* __restrict__ bn, const unsigned short* __restrict__ IG,
    uint* __restrict__ hbuf, float* __restrict__ hfin) {
  const int tid = threadIdx.x;
  const int lane = tid & 63;
  const int w = tid >> 6;          // wave 0..3
  const int l15 = lane & 15, q = lane >> 4;
  const int g = blockIdx.x >> 3;   // 8 groups of 16 batch rows
  const int cb = blockIdx.x & 7;   // 8 col-chunks of 64
  const int col = cb * 64 + w * 16 + l15;  // this lane's h column
  const int cc = cb * 4 + w;               // col-16-chunk id (IG layout)
  const int mrow = g * 16 + l15;           // A-fragment batch row
  const int erow = g * 16 + q * 4;         // C-layout batch row base

  // Whh B-fragments -> registers: 3 gates x 16 k-chunks (192 VGPRs)
  short8 bfr[3][16];
#pragma unroll
  for (int gt = 0; gt < 3; ++gt) {
    const float* src = Whh + (size_t)(gt * NH + col) * NH + q * 8;
#pragma unroll
    for (int kk = 0; kk < 16; ++kk) {
      float4 v0 = *(const float4*)(src + kk * 32);
      float4 v1 = *(const float4*)(src + kk * 32 + 4);
      bfr[gt][kk] = pack8(v0, v1);
    }
  }

  float bi_r = 0.f, bi_z = 0.f, bi_n = 0.f;
  if (!USE_IG) {
    bi_r = bias[col];
    bi_z = bias[NH + col];
    bi_n = bias[2 * NH + col];
  }
  const float bnv = bn[col];

  float hreg[4] = {0.f, 0.f, 0.f, 0.f};

  uint* const hb0 = hbuf;
  uint* const hb1 = hbuf + NB * NH;

  // preload IG[0]
  uint2 cr = {}, cz = {}, cn = {};
  if (USE_IG) {
    const unsigned short* p0 =
        IG + (((size_t)g * NT + 0) * 32 + cc) * 768 + (size_t)(q * 16 + l15) * 4;
    cr = *(const uint2*)p0;
    cz = *(const uint2*)(p0 + 256);
    cn = *(const uint2*)(p0 + 512);
  }

  for (int t = 0; t < NT; ++t) {
    // prefetch IG[t+1] (plain loads; in flight across the h retry loop)
    uint2 nr = {}, nz = {}, nn = {};
    if (USE_IG) {
      int tn_ = (t + 1 < NT) ? t + 1 : t;
      const unsigned short* pn =
          IG + (((size_t)g * NT + tn_) * 32 + cc) * 768 + (size_t)(q * 16 + l15) * 4;
      nr = *(const uint2*)pn;
      nz = *(const uint2*)(pn + 256);
      nn = *(const uint2*)(pn + 512);
    }

    // fallback: x@Wih^T (independent of h; also serves as skew filler)
    f32x4 axr = {0.f, 0.f, 0.f, 0.f};
    f32x4 axz = {0.f, 0.f, 0.f, 0.f};
    f32x4 axn = {0.f, 0.f, 0.f, 0.f};
    if (!USE_IG) {
#pragma unroll
      for (int kk = 0; kk < 16; ++kk) {
        const float* xp = x + ((size_t)mrow * NT + t) * ND + kk * 32 + q * 8;
        short8 xa = pack8(*(const float4*)xp, *(const float4*)(xp + 4));
#pragma unroll
        for (int gt = 0; gt < 3; ++gt) {
          const float* wp = Wih + (size_t)(gt * NH + col) * ND + kk * 32 + q * 8;
          short8 wf = pack8(*(const float4*)wp, *(const float4*)(wp + 4));
          if (gt == 0) axr = __builtin_amdgcn_mfma_f32_16x16x32_bf16(xa, wf, axr, 0, 0, 0);
          if (gt == 1) axz = __builtin_amdgcn_mfma_f32_16x16x32_bf16(xa, wf, axz, 0, 0, 0);
          if (gt == 2) axn = __builtin_amdgcn_mfma_f32_16x16x32_bf16(xa, wf, axn, 0, 0, 0);
        }
      }
    }

    // h @ Whh^T with tag validation BEFORE compute; retry = reload only.
    f32x4 ar = {0.f, 0.f, 0.f, 0.f};
    f32x4 az = {0.f, 0.f, 0.f, 0.f};
    f32x4 an = {0.f, 0.f, 0.f, 0.f};
    if (t > 0) {
      const uint* hp = ((t & 1) ? hb1 : hb0) + (size_t)mrow * NH + q * 8;
      const uint tt = (uint)t;
      int4v ra[16], rb[16];
      uint bad;
      do {
        load16_a(hp, ra);
        load16_b(hp, rb);  // ends s_waitcnt vmcnt(0)
        uint acc_ = 0;
#pragma unroll
        for (int j = 0; j < 16; ++j) {
          acc_ |= (uint)ra[j][0] ^ tt; acc_ |= (uint)ra[j][1] ^ tt;
          acc_ |= (uint)ra[j][2] ^ tt; acc_ |= (uint)ra[j][3] ^ tt;
          acc_ |= (uint)rb[j][0] ^ tt; acc_ |= (uint)rb[j][1] ^ tt;
          acc_ |= (uint)rb[j][2] ^ tt; acc_ |= (uint)rb[j][3] ^ tt;
        }
        bad = acc_ & 0xffffu;
      } while (__any((int)bad));
#pragma unroll
      for (int kk = 0; kk < 8; ++kk) {
        short8 afk = unpack8(ra[2 * kk], ra[2 * kk + 1]);
        ar = __builtin_amdgcn_mfma_f32_16x16x32_bf16(afk, bfr[0][kk], ar, 0, 0, 0);
        az = __builtin_amdgcn_mfma_f32_16x16x32_bf16(afk, bfr[1][kk], az, 0, 0, 0);
        an = __builtin_amdgcn_mfma_f32_16x16x32_bf16(afk, bfr[2][kk], an, 0, 0, 0);
      }
#pragma unroll
      for (int kk = 0; kk < 8; ++kk) {
        short8 afk = unpack8(rb[2 * kk], rb[2 * kk + 1]);
        ar = __builtin_amdgcn_mfma_f32_16x16x32_bf16(afk, bfr[0][8 + kk], ar, 0, 0, 0);
        az = __builtin_amdgcn_mfma_f32_16x16x32_bf16(afk, bfr[1][8 + kk], az, 0, 0, 0);
        an = __builtin_amdgcn_mfma_f32_16x16x32_bf16(afk, bfr[2][8 + kk], an, 0, 0, 0);
      }
    }

    // gates + h update
    float igr[4], igz[4], ign[4];
    if (USE_IG) {
      igr[0] = bf2f((unsigned short)(cr.x & 0xffff));
      igr[1] = bf2f((unsigned short)(cr.x >> 16));
      igr[2] = bf2f((unsigned short)(cr.y & 0xffff));
      igr[3] = bf2f((unsigned short)(cr.y >> 16));
      igz[0] = bf2f((unsigned short)(cz.x & 0xffff));
      igz[1] = bf2f((unsigned short)(cz.x >> 16));
      igz[2] = bf2f((unsigned short)(cz.y & 0xffff));
      igz[3] = bf2f((unsigned short)(cz.y >> 16));
      ign[0] = bf2f((unsigned short)(cn.x & 0xffff));
      ign[1] = bf2f((unsigned short)(cn.x >> 16));
      ign[2] = bf2f((unsigned short)(cn.y & 0xffff));
      ign[3] = bf2f((unsigned short)(cn.y >> 16));
    }
    uint sv[4];
#pragma unroll
    for (int i = 0; i < 4; ++i) {
      float xr = ar[i] + (USE_IG ? igr[i] : (axr[i] + bi_r));
      float xz = az[i] + (USE_IG ? igz[i] : (axz[i] + bi_z));
      float xin = USE_IG ? ign[i] : (axn[i] + bi_n);
      float r = sigmoid_f(xr);
      float z = sigmoid_f(xz);
      float n = tanh_f(xin + r * (an[i] + bnv));
      float h2 = (1.f - z) * n + z * hreg[i];
      hreg[i] = h2;
      sv[i] = ((uint)f2bf(h2) << 16) | (uint)(t + 1);
      if (t == NT - 1) hfin[(size_t)(erow + i) * NH + col] = h2;
    }
    if (t != NT - 1) {
      uint* p0 = ((t & 1) ? hb0 : hb1) + (size_t)erow * NH + col;
      uint* p1 = p0 + 2 * NH;
      asm volatile(
          "global_store_dword %0, %2, off sc0 sc1\n\t"
          "global_store_dword %0, %3, off offset:2048 sc0 sc1\n\t"
          "global_store_dword %1, %4, off sc0 sc1\n\t"
          "global_store_dword %1, %5, off offset:2048 sc0 sc1"
          :
          : "v"(p0), "v"(p1), "v"(sv[0]), "v"(sv[1]), "v"(sv[2]), "v"(sv[3])
          : "memory");
    }
    cr = nr; cz = nz; cn = nn;
  }
}

// ---------------------------------------------------------------------------
// out = h_T @ Wlin^T + blin; mu = cols [0,256), logvar = cols [256,512).
// ---------------------------------------------------------------------------
__global__ __launch_bounds__(256) void final_linear(
    const float* __restrict__ hfin, const float* __restrict__ Wlin,
    const float* __restrict__ blin, float* __restrict__ out) {
  __shared__ float sh[16 * 516];
  const int tid = threadIdx.x;
  const int b0 = blockIdx.y * 16, o0 = blockIdx.x * 16;

  for (int j = tid; j < 16 * 128; j += 256) {
    int row = j >> 7, kq = j & 127;
    *(float4*)&sh[row * 516 + kq * 4] =
        *(const float4*)(hfin + (size_t)(b0 + row) * NH + kq * 4);
  }
  __syncthreads();

  const int bi = tid & 15, oi = tid >> 4;
  const int o = o0 + oi;
  const float4* wp = (const float4*)(Wlin + (size_t)o * NH);
  float4 a4 = {0.f, 0.f, 0.f, 0.f};
  for (int k4 = 0; k4 < 128; ++k4) {
    float4 wv = wp[k4];
    float4 hv = *(const float4*)&sh[bi * 516 + k4 * 4];
    a4.x += wv.x * hv.x; a4.y += wv.y * hv.y;
    a4.z += wv.z * hv.z; a4.w += wv.w * hv.w;
  }
  float v = a4.x + a4.y + a4.z + a4.w + blin[o];
  int b = b0 + bi;
  if (o < 256) out[b * 256 + o] = v;
  else out[32768 + b * 256 + (o - 256)] = v;
}

// ---------------------------------------------------------------------------
extern "C" void kernel_launch(void* const* d_in, const int* in_sizes, int n_in,
                              void* d_out, int out_size, void* d_ws, size_t ws_size,
                              hipStream_t stream) {
  const float* x    = (const float*)d_in[0];
  const float* Wih  = (const float*)d_in[1];
  const float* Whh  = (const float*)d_in[2];
  const float* bias = (const float*)d_in[3];
  const float* bn   = (const float*)d_in[4];
  const float* Wlin = (const float*)d_in[5];
  const float* blin = (const float*)d_in[6];
  float* out = (float*)d_out;

  char* ws = (char*)d_ws;
  // layout: [h32 dword dbuf 524288][hfin 262144][IG 201326592]
  uint* hbuf          = (uint*)ws;
  float* hfin         = (float*)(ws + 524288);
  unsigned short* IG  = (unsigned short*)(ws + 786432);
  const size_t need_min = 786432;
  const size_t need_ig  = 786432 + (size_t)NB * NT * NG * 2;  // ~203 MB
  if (ws_size < need_min) return;
  // no memsets: t=0 skips h reads; tag scheme rejects 0xAA poison.

  const bool useIG = (ws_size >= need_ig);
  if (useIG) {
    ig_gemm<<<dim3(512, 12), 256, 0, stream>>>(x, Wih, bias, IG);
    gru_rec<true><<<64, 256, 0, stream>>>(x, Wih, Whh, bias, bn, IG, hbuf, hfin);
  } else {
    gru_rec<false><<<64, 256, 0, stream>>>(x, Wih, Whh, bias, bn, nullptr, hbuf, hfin);
  }
  final_linear<<<dim3(32, 8), 256, 0, stream>>>(hfin, Wlin, blin, out);
}

// Round 7
// 3151.499 us; speedup vs baseline: 1.3249x; 1.2785x over previous
//
#include <hip/hip_runtime.h>
#include <stdint.h>

// ---------------------------------------------------------------------------
// GRU encoder (B=128,T=512,D=512,H=512,L=256), MI355X gfx950.
//
// R7: tag-in-data + cooperative block load + timed first attempt.
//  - block coop-loads the 16x512 tagged h slice ONCE (8 dwordx4/thread),
//    validates per-thread (63 VALU), votes via __syncthreads_or; retry =
//    reload 8 loads + re-vote (cheap). s_sleep(4) before first try so the
//    load services after producer stores arrive at the coherence point.
//  - validated dwords stripped (v_perm) into LDS (pad 520), waves read
//    A-frags via ds_read_b128 (2-way banks = free).
//  - producer: 4 fire-and-forget sc0 sc1 dword stores, tag = t+1. No drains,
//    no flags, no memsets (poison 0xAAAA != any tag; t=0 skips h).
//  - safety: same induction as R5/R6 — overwrite of buf requires all waves
//    stored h_{t+1}, which requires their h_t reads completed.
// ---------------------------------------------------------------------------

typedef short short8 __attribute__((ext_vector_type(8)));
typedef float f32x4 __attribute__((ext_vector_type(4)));
typedef int int4v __attribute__((ext_vector_type(4)));
typedef unsigned int uint;

#define NB 128
#define NT 512
#define ND 512
#define NH 512
#define NG 1536  // 3H

__device__ __forceinline__ unsigned short f2bf(float f) {
  union { float f; unsigned u; } v; v.f = f;
  unsigned r = v.u + 0x7fffu + ((v.u >> 16) & 1u);  // RNE
  return (unsigned short)(r >> 16);
}
__device__ __forceinline__ float bf2f(unsigned short u) {
  union { unsigned u; float f; } v; v.u = ((unsigned)u) << 16; return v.f;
}
__device__ __forceinline__ float sigmoid_f(float x) {
  float e = __builtin_amdgcn_exp2f(-1.4426950408889634f * x);
  return __builtin_amdgcn_rcpf(1.0f + e);
}
__device__ __forceinline__ float tanh_f(float x) {
  float e = __builtin_amdgcn_exp2f(2.8853900817779268f * x);
  return 1.0f - 2.0f * __builtin_amdgcn_rcpf(1.0f + e);
}
__device__ __forceinline__ short8 pack8(float4 a, float4 b) {
  short8 s;
  s[0] = (short)f2bf(a.x); s[1] = (short)f2bf(a.y);
  s[2] = (short)f2bf(a.z); s[3] = (short)f2bf(a.w);
  s[4] = (short)f2bf(b.x); s[5] = (short)f2bf(b.y);
  s[6] = (short)f2bf(b.z); s[7] = (short)f2bf(b.w);
  return s;
}

// 8 coherent dwordx4 loads (this thread's 32 tagged dwords) + drain.
__device__ __forceinline__ void coop_load8(const uint* p, int4v a[8]) {
  asm volatile(
      "global_load_dwordx4 %0, %8, off sc0 sc1\n\t"
      "global_load_dwordx4 %1, %8, off offset:16 sc0 sc1\n\t"
      "global_load_dwordx4 %2, %8, off offset:32 sc0 sc1\n\t"
      "global_load_dwordx4 %3, %8, off offset:48 sc0 sc1\n\t"
      "global_load_dwordx4 %4, %8, off offset:64 sc0 sc1\n\t"
      "global_load_dwordx4 %5, %8, off offset:80 sc0 sc1\n\t"
      "global_load_dwordx4 %6, %8, off offset:96 sc0 sc1\n\t"
      "global_load_dwordx4 %7, %8, off offset:112 sc0 sc1\n\t"
      "s_waitcnt vmcnt(0)"
      : "=&v"(a[0]), "=&v"(a[1]), "=&v"(a[2]), "=&v"(a[3]),
        "=&v"(a[4]), "=&v"(a[5]), "=&v"(a[6]), "=&v"(a[7])
      : "v"(p)
      : "memory");
}

__device__ __forceinline__ uint tagacc(const int4v r[8], uint tt) {
  uint a = 0;
#pragma unroll
  for (int j = 0; j < 8; ++j) {
    a |= ((uint)r[j][0] ^ tt); a |= ((uint)r[j][1] ^ tt);
    a |= ((uint)r[j][2] ^ tt); a |= ((uint)r[j][3] ^ tt);
  }
  return a;
}

// ---------------------------------------------------------------------------
// IG = x @ Wih^T + bias, bf16, wave-tile layout (verified R5/R6):
// IG[(((g*NT+t)*32+cc)*3+gt)*256 + (q*16+l15)*4 + i]
// ---------------------------------------------------------------------------
__global__ __launch_bounds__(256) void ig_gemm(
    const float* __restrict__ x, const float* __restrict__ Wih,
    const float* __restrict__ bias, unsigned short* __restrict__ IG) {
  __shared__ unsigned short As[128 * 40];
  __shared__ unsigned short Bs[128 * 40];
  const int tid = threadIdx.x;
  const int bm = blockIdx.x, bn = blockIdx.y;
  const int lane = tid & 63, w = tid >> 6;
  const int wm = w >> 1, wn = w & 1;
  const int l15 = lane & 15, q = lane >> 4;

  f32x4 acc[4][4] = {};

  for (int kt = 0; kt < 16; ++kt) {
    __syncthreads();
#pragma unroll
    for (int j = 0; j < 4; ++j) {
      int fi = tid + 256 * j;
      int row = fi >> 3, kq = fi & 7;
      float4 v = *(const float4*)(x + (size_t)(bm * 128 + row) * ND + kt * 32 + kq * 4);
      ushort4 s = {f2bf(v.x), f2bf(v.y), f2bf(v.z), f2bf(v.w)};
      *(ushort4*)&As[row * 40 + kq * 4] = s;
    }
#pragma unroll
    for (int j = 0; j < 4; ++j) {
      int fi = tid + 256 * j;
      int row = fi >> 3, kq = fi & 7;
      float4 v = *(const float4*)(Wih + (size_t)(bn * 128 + row) * ND + kt * 32 + kq * 4);
      ushort4 s = {f2bf(v.x), f2bf(v.y), f2bf(v.z), f2bf(v.w)};
      *(ushort4*)&Bs[row * 40 + kq * 4] = s;
    }
    __syncthreads();

    short8 af[4], bf[4];
#pragma unroll
    for (int tm = 0; tm < 4; ++tm)
      af[tm] = *(const short8*)&As[(wm * 64 + tm * 16 + l15) * 40 + q * 8];
#pragma unroll
    for (int tn = 0; tn < 4; ++tn)
      bf[tn] = *(const short8*)&Bs[(wn * 64 + tn * 16 + l15) * 40 + q * 8];
#pragma unroll
    for (int tm = 0; tm < 4; ++tm)
#pragma unroll
      for (int tn = 0; tn < 4; ++tn)
        acc[tm][tn] = __builtin_amdgcn_mfma_f32_16x16x32_bf16(af[tm], bf[tn], acc[tm][tn], 0, 0, 0);
  }

  const int b = bm >> 2;
  const int bt_ = b >> 4, qc = (b >> 2) & 3, ic = b & 3;
  const int tb = (bm & 3) * 128 + wm * 64;
#pragma unroll
  for (int tm = 0; tm < 4; ++tm) {
#pragma unroll
    for (int tn = 0; tn < 4; ++tn) {
      int C = bn * 128 + wn * 64 + tn * 16 + l15;
      int gt_ = C >> 9, hcol = C & 511, cc_ = hcol >> 4;
      float bb = bias[C];
#pragma unroll
      for (int i = 0; i < 4; ++i) {
        int t = tb + tm * 16 + q * 4 + i;
        size_t idx = ((((size_t)bt_ * NT + t) * 32 + cc_) * 3 + gt_) * 256
                     + (size_t)(qc * 16 + l15) * 4 + ic;
        IG[idx] = f2bf(acc[tm][tn][i] + bb);
      }
    }
  }
}

// ---------------------------------------------------------------------------
// Persistent GRU recurrence. 64 blocks x 256 threads.
// block = (group g: 16 batch rows, chunk cb: 64 h-cols). wave w: 16 cols.
// ---------------------------------------------------------------------------
template <bool USE_IG>
__global__ __launch_bounds__(256, 1) void gru_rec(
    const float* __restrict__ x, const float* __restrict__ Wih,
    const float* __restrict__ Whh, const float* __restrict__ bias,
    const float* __restrict__ bn, const unsigned short* __restrict__ IG,
    uint* __restrict__ hbuf, float* __restrict__ hfin) {
  const int tid = threadIdx.x;
  const int lane = tid & 63;
  const int w = tid >> 6;          // wave 0..3
  const int l15 = lane & 15, q = lane >> 4;
  const int g = blockIdx.x >> 3;   // 8 groups of 16 batch rows
  const int cb = blockIdx.x & 7;   // 8 col-chunks of 64
  const int col = cb * 64 + w * 16 + l15;  // this lane's h column
  const int cc = cb * 4 + w;               // col-16-chunk id (IG layout)
  const int mrow = g * 16 + l15;           // A-fragment batch row
  const int erow = g * 16 + q * 4;         // C-layout batch row base
  const int lrow = tid >> 4;               // coop loader: local row 0..15
  const int lseg = tid & 15;               // coop loader: 32-dword segment

  __shared__ unsigned short hA[16 * 520];  // stripped bf16 h, pad 512->520

  // Whh B-fragments -> registers: 3 gates x 16 k-chunks (192 VGPRs)
  short8 bfr[3][16];
#pragma unroll
  for (int gt = 0; gt < 3; ++gt) {
    const float* src = Whh + (size_t)(gt * NH + col) * NH + q * 8;
#pragma unroll
    for (int kk = 0; kk < 16; ++kk) {
      float4 v0 = *(const float4*)(src + kk * 32);
      float4 v1 = *(const float4*)(src + kk * 32 + 4);
      bfr[gt][kk] = pack8(v0, v1);
    }
  }

  float bi_r = 0.f, bi_z = 0.f, bi_n = 0.f;
  if (!USE_IG) {
    bi_r = bias[col];
    bi_z = bias[NH + col];
    bi_n = bias[2 * NH + col];
  }
  const float bnv = bn[col];

  float hreg[4] = {0.f, 0.f, 0.f, 0.f};

  uint* const hb0 = hbuf;
  uint* const hb1 = hbuf + NB * NH;

  // preload IG[0]
  uint2 cr = {}, cz = {}, cn = {};
  if (USE_IG) {
    const unsigned short* p0 =
        IG + (((size_t)g * NT + 0) * 32 + cc) * 768 + (size_t)(q * 16 + l15) * 4;
    cr = *(const uint2*)p0;
    cz = *(const uint2*)(p0 + 256);
    cn = *(const uint2*)(p0 + 512);
  }

  for (int t = 0; t < NT; ++t) {
    // prefetch IG[t+1] (plain loads; complete under the h-load wait)
    uint2 nr = {}, nz = {}, nn = {};
    if (USE_IG) {
      int tn_ = (t + 1 < NT) ? t + 1 : t;
      const unsigned short* pn =
          IG + (((size_t)g * NT + tn_) * 32 + cc) * 768 + (size_t)(q * 16 + l15) * 4;
      nr = *(const uint2*)pn;
      nz = *(const uint2*)(pn + 256);
      nn = *(const uint2*)(pn + 512);
    }

    // fallback: x@Wih^T (independent of h)
    f32x4 axr = {0.f, 0.f, 0.f, 0.f};
    f32x4 axz = {0.f, 0.f, 0.f, 0.f};
    f32x4 axn = {0.f, 0.f, 0.f, 0.f};
    if (!USE_IG) {
#pragma unroll
      for (int kk = 0; kk < 16; ++kk) {
        const float* xp = x + ((size_t)mrow * NT + t) * ND + kk * 32 + q * 8;
        short8 xa = pack8(*(const float4*)xp, *(const float4*)(xp + 4));
#pragma unroll
        for (int gt = 0; gt < 3; ++gt) {
          const float* wp = Wih + (size_t)(gt * NH + col) * ND + kk * 32 + q * 8;
          short8 wf = pack8(*(const float4*)wp, *(const float4*)(wp + 4));
          if (gt == 0) axr = __builtin_amdgcn_mfma_f32_16x16x32_bf16(xa, wf, axr, 0, 0, 0);
          if (gt == 1) axz = __builtin_amdgcn_mfma_f32_16x16x32_bf16(xa, wf, axz, 0, 0, 0);
          if (gt == 2) axn = __builtin_amdgcn_mfma_f32_16x16x32_bf16(xa, wf, axn, 0, 0, 0);
        }
      }
    }

    // h @ Whh^T via coop load + block vote + LDS
    f32x4 ar = {0.f, 0.f, 0.f, 0.f};
    f32x4 az = {0.f, 0.f, 0.f, 0.f};
    f32x4 an = {0.f, 0.f, 0.f, 0.f};
    if (t > 0) {
      const uint* cp = ((t & 1) ? hb1 : hb0) + (size_t)(g * 16 + lrow) * NH + lseg * 32;
      const uint tt = (uint)t;
      int4v raw[8];
      __builtin_amdgcn_s_sleep(4);  // ~256 cy: let producer stores land
      coop_load8(cp, raw);
      uint acc_ = tagacc(raw, tt);
      while (__syncthreads_or((int)(acc_ & 0xffffu))) {
        __builtin_amdgcn_s_sleep(1);
        coop_load8(cp, raw);
        acc_ = tagacc(raw, tt);
      }
      // strip tags -> LDS (bf16). 32 dwords -> 32 shorts per thread.
      unsigned short* dst = &hA[lrow * 520 + lseg * 32];
#pragma unroll
      for (int j = 0; j < 4; ++j) {
        int4v s;
        s[0] = (int)__builtin_amdgcn_perm((uint)raw[2 * j][1], (uint)raw[2 * j][0], 0x07060302u);
        s[1] = (int)__builtin_amdgcn_perm((uint)raw[2 * j][3], (uint)raw[2 * j][2], 0x07060302u);
        s[2] = (int)__builtin_amdgcn_perm((uint)raw[2 * j + 1][1], (uint)raw[2 * j + 1][0], 0x07060302u);
        s[3] = (int)__builtin_amdgcn_perm((uint)raw[2 * j + 1][3], (uint)raw[2 * j + 1][2], 0x07060302u);
        *(int4v*)(dst + j * 8) = s;
      }
      __syncthreads();
#pragma unroll
      for (int kk = 0; kk < 16; ++kk) {
        short8 afk = *(const short8*)&hA[l15 * 520 + kk * 32 + q * 8];
        ar = __builtin_amdgcn_mfma_f32_16x16x32_bf16(afk, bfr[0][kk], ar, 0, 0, 0);
        az = __builtin_amdgcn_mfma_f32_16x16x32_bf16(afk, bfr[1][kk], az, 0, 0, 0);
        an = __builtin_amdgcn_mfma_f32_16x16x32_bf16(afk, bfr[2][kk], an, 0, 0, 0);
      }
    }

    // gates + h update
    float igr[4], igz[4], ign[4];
    if (USE_IG) {
      igr[0] = bf2f((unsigned short)(cr.x & 0xffff));
      igr[1] = bf2f((unsigned short)(cr.x >> 16));
      igr[2] = bf2f((unsigned short)(cr.y & 0xffff));
      igr[3] = bf2f((unsigned short)(cr.y >> 16));
      igz[0] = bf2f((unsigned short)(cz.x & 0xffff));
      igz[1] = bf2f((unsigned short)(cz.x >> 16));
      igz[2] = bf2f((unsigned short)(cz.y & 0xffff));
      igz[3] = bf2f((unsigned short)(cz.y >> 16));
      ign[0] = bf2f((unsigned short)(cn.x & 0xffff));
      ign[1] = bf2f((unsigned short)(cn.x >> 16));
      ign[2] = bf2f((unsigned short)(cn.y & 0xffff));
      ign[3] = bf2f((unsigned short)(cn.y >> 16));
    }
    uint sv[4];
#pragma unroll
    for (int i = 0; i < 4; ++i) {
      float xr = ar[i] + (USE_IG ? igr[i] : (axr[i] + bi_r));
      float xz = az[i] + (USE_IG ? igz[i] : (axz[i] + bi_z));
      float xin = USE_IG ? ign[i] : (axn[i] + bi_n);
      float r = sigmoid_f(xr);
      float z = sigmoid_f(xz);
      float n = tanh_f(xin + r * (an[i] + bnv));
      float h2 = (1.f - z) * n + z * hreg[i];
      hreg[i] = h2;
      sv[i] = ((uint)f2bf(h2) << 16) | (uint)(t + 1);
      if (t == NT - 1) hfin[(size_t)(erow + i) * NH + col] = h2;
    }
    if (t != NT - 1) {
      uint* p0 = ((t & 1) ? hb0 : hb1) + (size_t)erow * NH + col;
      uint* p1 = p0 + 2 * NH;
      asm volatile(
          "global_store_dword %0, %2, off sc0 sc1\n\t"
          "global_store_dword %0, %3, off offset:2048 sc0 sc1\n\t"
          "global_store_dword %1, %4, off sc0 sc1\n\t"
          "global_store_dword %1, %5, off offset:2048 sc0 sc1"
          :
          : "v"(p0), "v"(p1), "v"(sv[0]), "v"(sv[1]), "v"(sv[2]), "v"(sv[3])
          : "memory");
    }
    cr = nr; cz = nz; cn = nn;
  }
}

// ---------------------------------------------------------------------------
// out = h_T @ Wlin^T + blin; mu = cols [0,256), logvar = cols [256,512).
// ---------------------------------------------------------------------------
__global__ __launch_bounds__(256) void final_linear(
    const float* __restrict__ hfin, const float* __restrict__ Wlin,
    const float* __restrict__ blin, float* __restrict__ out) {
  __shared__ float sh[16 * 516];
  const int tid = threadIdx.x;
  const int b0 = blockIdx.y * 16, o0 = blockIdx.x * 16;

  for (int j = tid; j < 16 * 128; j += 256) {
    int row = j >> 7, kq = j & 127;
    *(float4*)&sh[row * 516 + kq * 4] =
        *(const float4*)(hfin + (size_t)(b0 + row) * NH + kq * 4);
  }
  __syncthreads();

  const int bi = tid & 15, oi = tid >> 4;
  const int o = o0 + oi;
  const float4* wp = (const float4*)(Wlin + (size_t)o * NH);
  float4 a4 = {0.f, 0.f, 0.f, 0.f};
  for (int k4 = 0; k4 < 128; ++k4) {
    float4 wv = wp[k4];
    float4 hv = *(const float4*)&sh[bi * 516 + k4 * 4];
    a4.x += wv.x * hv.x; a4.y += wv.y * hv.y;
    a4.z += wv.z * hv.z; a4.w += wv.w * hv.w;
  }
  float v = a4.x + a4.y + a4.z + a4.w + blin[o];
  int b = b0 + bi;
  if (o < 256) out[b * 256 + o] = v;
  else out[32768 + b * 256 + (o - 256)] = v;
}

// ---------------------------------------------------------------------------
extern "C" void kernel_launch(void* const* d_in, const int* in_sizes, int n_in,
                              void* d_out, int out_size, void* d_ws, size_t ws_size,
                              hipStream_t stream) {
  const float* x    = (const float*)d_in[0];
  const float* Wih  = (const float*)d_in[1];
  const float* Whh  = (const float*)d_in[2];
  const float* bias = (const float*)d_in[3];
  const float* bn   = (const float*)d_in[4];
  const float* Wlin = (const float*)d_in[5];
  const float* blin = (const float*)d_in[6];
  float* out = (float*)d_out;

  char* ws = (char*)d_ws;
  // layout: [h32 dword dbuf 524288][hfin 262144][IG 201326592]
  uint* hbuf          = (uint*)ws;
  float* hfin         = (float*)(ws + 524288);
  unsigned short* IG  = (unsigned short*)(ws + 786432);
  const size_t need_min = 786432;
  const size_t need_ig  = 786432 + (size_t)NB * NT * NG * 2;  // ~203 MB
  if (ws_size < need_min) return;
  // no memsets: t=0 skips h reads; tag scheme rejects 0xAA poison.

  const bool useIG = (ws_size >= need_ig);
  if (useIG) {
    ig_gemm<<<dim3(512, 12), 256, 0, stream>>>(x, Wih, bias, IG);
    gru_rec<true><<<64, 256, 0, stream>>>(x, Wih, Whh, bias, bn, IG, hbuf, hfin);
  } else {
    gru_rec<false><<<64, 256, 0, stream>>>(x, Wih, Whh, bias, bn, nullptr, hbuf, hfin);
  }
  final_linear<<<dim3(32, 8), 256, 0, stream>>>(hfin, Wlin, blin, out);
}